// Round 13
// baseline (139.530 us; speedup 1.0000x reference)
//
#include <hip/hip_runtime.h>
#include <cstdint>
#include <cstddef>

typedef float f32x4 __attribute__((ext_vector_type(4)));
typedef float f32x16 __attribute__((ext_vector_type(16)));
typedef __bf16 bf16x8 __attribute__((ext_vector_type(8)));
typedef __bf16 bf16x4 __attribute__((ext_vector_type(4)));
typedef uint32_t u32x4 __attribute__((ext_vector_type(4)));

static constexpr int BSZ = 2, SL = 2048, DM = 1024, NH = 16, HD = 64;
static constexpr int MROWS = BSZ * SL;                 // 4096
static constexpr float LOG2E = 1.4426950408889634f;
static constexpr float QSCALE = 0.03125f * LOG2E;      // D^-0.5 * log2(e)

__device__ __forceinline__ f32x4 mfma16(bf16x8 a, bf16x8 b, f32x4 c) {
    return __builtin_amdgcn_mfma_f32_16x16x32_bf16(a, b, c, 0, 0, 0);
}
__device__ __forceinline__ f32x16 mfma32(bf16x8 a, bf16x8 b, f32x16 c) {
    return __builtin_amdgcn_mfma_f32_32x32x16_bf16(a, b, c, 0, 0, 0);
}
__device__ __forceinline__ uint32_t pkbf(float lo, float hi) {
    uint16_t a = __builtin_bit_cast(uint16_t, (__bf16)lo);
    uint16_t b = __builtin_bit_cast(uint16_t, (__bf16)hi);
    return ((uint32_t)b << 16) | (uint32_t)a;
}
// raw v_exp_f32 (2^x); inputs bounded, no denormal guard needed (r10-proven)
__device__ __forceinline__ float fexp2(float x) {
#if __has_builtin(__builtin_amdgcn_exp2f)
    return __builtin_amdgcn_exp2f(x);
#else
    float r; asm volatile("v_exp_f32 %0, %1" : "=v"(r) : "v"(x)); return r;
#endif
}
// async global->LDS, 16B per lane; lds dest = wave-uniform base + lane*16
__device__ __forceinline__ void gload16(const void* g, void* l) {
    __builtin_amdgcn_global_load_lds(
        (const __attribute__((address_space(1))) uint32_t*)g,
        (__attribute__((address_space(3))) uint32_t*)l, 16, 0, 0);
}

// ---------- cast f32 -> bf16, vectorized x4 ----------
__global__ __launch_bounds__(256) void r13_cast(const float* __restrict__ in,
                                                __bf16* __restrict__ out, int n) {
    int i = (blockIdx.x * 256 + threadIdx.x) * 4;
    if (i >= n) return;
    float4 v = *(const float4*)&in[i];
    bf16x4 o;
    o.x = (__bf16)v.x; o.y = (__bf16)v.y; o.z = (__bf16)v.z; o.w = (__bf16)v.w;
    *(bf16x4*)&out[i] = o;
}

// ---------- transpose [R][C] f32 -> [C][R] bf16 ----------
__global__ __launch_bounds__(256) void r13_transpose_cast(const float* __restrict__ in,
                                                          __bf16* __restrict__ out,
                                                          int R, int C) {
    __shared__ float tile[32][33];
    int c0 = blockIdx.x * 32, r0 = blockIdx.y * 32;
    int tx = threadIdx.x & 31, ty = threadIdx.x >> 5;   // 256 threads: ty 0..7
#pragma unroll
    for (int i = 0; i < 32; i += 8)
        tile[ty + i][tx] = in[(size_t)(r0 + ty + i) * C + c0 + tx];
    __syncthreads();
#pragma unroll
    for (int i = 0; i < 32; i += 8)
        out[(size_t)(c0 + ty + i) * R + r0 + tx] = (__bf16)tile[tx][ty + i];
}

// ---------- GEMM (r10-proven, BK=32, global_load_lds): C = A * Bt^T ----------
// EPI==1: scatter into Q (scaled), K, V^T.  EPI==0: f32 row-major out.
template <int EPI, int BN>
__global__ __launch_bounds__(256) void r13_gemm(
    const __bf16* __restrict__ A, const __bf16* __restrict__ Bt,
    float* __restrict__ ob, int M, int N, int K,
    __bf16* __restrict__ qb, __bf16* __restrict__ kb, __bf16* __restrict__ vtb)
{
    constexpr int BM = 128, BK = 32;
    constexpr int FN = BN / 32;               // acc cols per wave (128->4, 64->2)
    __shared__ __bf16 As[BM * BK];
    __shared__ __bf16 Bs[BN * BK];
    const int tid  = threadIdx.x;
    const int m0   = blockIdx.y * BM, n0 = blockIdx.x * BN;
    const int wave = tid >> 6, lane = tid & 63;
    const int lcol = lane & 15, lgrp = lane >> 4;
    const int wm   = (wave >> 1) * 64, wn = (wave & 1) * (BN / 2);
    const int grow = lane >> 2, gcol = (lane & 3) * 8;   // staging: 16 rows/chunk

    f32x4 acc[4][FN] = {};

    for (int k0 = 0; k0 < K; k0 += BK) {
        {
            const int cA0 = 2 * wave;
            gload16(&A[(size_t)(m0 + cA0 * 16 + grow) * K + k0 + gcol], &As[cA0 * 512]);
            gload16(&A[(size_t)(m0 + (cA0 + 1) * 16 + grow) * K + k0 + gcol], &As[(cA0 + 1) * 512]);
            if constexpr (BN == 128) {
                gload16(&Bt[(size_t)(n0 + cA0 * 16 + grow) * K + k0 + gcol], &Bs[cA0 * 512]);
                gload16(&Bt[(size_t)(n0 + (cA0 + 1) * 16 + grow) * K + k0 + gcol], &Bs[(cA0 + 1) * 512]);
            } else {
                gload16(&Bt[(size_t)(n0 + wave * 16 + grow) * K + k0 + gcol], &Bs[wave * 512]);
            }
        }
        __syncthreads();
        bf16x8 af[4], bfr[FN];
#pragma unroll
        for (int f = 0; f < 4; ++f)
            af[f] = *(const bf16x8*)&As[(wm + f * 16 + lcol) * BK + lgrp * 8];
#pragma unroll
        for (int f = 0; f < FN; ++f)
            bfr[f] = *(const bf16x8*)&Bs[(wn + f * 16 + lcol) * BK + lgrp * 8];
#pragma unroll
        for (int fm = 0; fm < 4; ++fm)
#pragma unroll
            for (int fn = 0; fn < FN; ++fn)
                acc[fm][fn] = mfma16(af[fm], bfr[fn], acc[fm][fn]);
        __syncthreads();
    }

#pragma unroll
    for (int fm = 0; fm < 4; ++fm) {
#pragma unroll
        for (int fn = 0; fn < FN; ++fn) {
            int n = n0 + wn + fn * 16 + lcol;
#pragma unroll
            for (int r = 0; r < 4; ++r) {
                int m = m0 + wm + fm * 16 + lgrp * 4 + r;
                float v = acc[fm][fn][r];
                if (EPI == 0) {
                    ob[(size_t)m * N + n] = v;               // f32 output
                } else {
                    int sec = n >> 10, nm = n & 1023;
                    int h = nm >> 6, d = nm & 63;
                    int b = m >> 11, s = m & 2047;
                    size_t bh = (size_t)(b * NH + h);
                    if (sec == 0)      qb[(bh * SL + s) * HD + d]  = (__bf16)(v * QSCALE);
                    else if (sec == 1) kb[(bh * SL + s) * HD + d]  = (__bf16)v;
                    else               vtb[(bh * HD + d) * SL + s] = (__bf16)v;
                }
            }
        }
    }
}

// ---------- flash attention: 64 q-rows/wave (2 col-groups), shared K/V frags -
// grid (8, 32) XCD-swizzled = 256 blocks; 4 waves x 64 q = 256 q/block.
// Each kf/vf LDS read now feeds 2 MFMAs -> LDS read volume per unit work halves.
#define PV2(PA, PB, O, KS) do {                                                 \
    uint32_t a0 = pkbf(PA[(O) + 0], PA[(O) + 1]);                               \
    uint32_t a1 = pkbf(PA[(O) + 2], PA[(O) + 3]);                               \
    uint32_t a2 = pkbf(PA[(O) + 4], PA[(O) + 5]);                               \
    uint32_t a3 = pkbf(PA[(O) + 6], PA[(O) + 7]);                               \
    asm volatile("v_permlane32_swap_b32 %0, %1" : "+v"(a0), "+v"(a2));          \
    asm volatile("v_permlane32_swap_b32 %0, %1" : "+v"(a1), "+v"(a3));          \
    u32x4 wa = {a0, a1, a2, a3};                                                \
    bf16x8 pfA = __builtin_bit_cast(bf16x8, wa);                                \
    uint32_t b0 = pkbf(PB[(O) + 0], PB[(O) + 1]);                               \
    uint32_t b1 = pkbf(PB[(O) + 2], PB[(O) + 3]);                               \
    uint32_t b2 = pkbf(PB[(O) + 4], PB[(O) + 5]);                               \
    uint32_t b3 = pkbf(PB[(O) + 6], PB[(O) + 7]);                               \
    asm volatile("v_permlane32_swap_b32 %0, %1" : "+v"(b0), "+v"(b2));          \
    asm volatile("v_permlane32_swap_b32 %0, %1" : "+v"(b1), "+v"(b3));          \
    u32x4 wb = {b0, b1, b2, b3};                                                \
    bf16x8 pfB = __builtin_bit_cast(bf16x8, wb);                                \
    const int cv = (((KS) * 2 + h) ^ swz8) * 8;                                 \
    bf16x8 vf0 = *(const bf16x8*)&Vl[lq * 64 + cv];                             \
    bf16x8 vf1 = *(const bf16x8*)&Vl[(lq + 32) * 64 + cv];                      \
    accT0 = mfma32(vf0, pfA, accT0);                                            \
    accT1 = mfma32(vf1, pfA, accT1);                                            \
    accT2 = mfma32(vf0, pfB, accT2);                                            \
    accT3 = mfma32(vf1, pfB, accT3);                                            \
} while (0)

// one KV-tile body; sync = lgkmcnt(0) + raw s_barrier + sched_barrier (r12-proven)
#define TILE_BODY(TI, KA, KB, VA, VB) do {                                      \
    const int cur = (TI) & 1;                                                   \
    {                                                                           \
        __bf16* dK = &arena[cur * 8192 + oA];                                   \
        __bf16* dV = dK + 4096;                                                 \
        *(int4*)dK = KA;  *(int4*)(dK + 2048) = KB;                             \
        *(int4*)dV = VA;  *(int4*)(dV + 2048) = VB;                             \
    }                                                                           \
    if ((TI) + 2 < NT) {                                                        \
        const __bf16* nK = KgA + (size_t)((TI) + 2) * 64 * HD;                  \
        const __bf16* nV = VgA + (size_t)((TI) + 2) * 64;                       \
        KA = *(const int4*)(nK);                                                \
        KB = *(const int4*)(nK + (size_t)32 * HD);                              \
        VA = *(const int4*)(nV);                                                \
        VB = *(const int4*)(nV + (size_t)32 * SL);                              \
    }                                                                           \
    asm volatile("s_waitcnt lgkmcnt(0)" ::: "memory");                          \
    __builtin_amdgcn_s_barrier();                                               \
    __builtin_amdgcn_sched_barrier(0);                                          \
    const __bf16* Kl = &arena[cur * 8192];                                      \
    const __bf16* Vl = Kl + 4096;                                               \
    f32x16 sA0 = {}, sA1 = {}, sB0 = {}, sB1 = {};                              \
    __builtin_amdgcn_s_setprio(1);                                              \
    _Pragma("unroll")                                                           \
    for (int t4 = 0; t4 < 4; ++t4) {                                            \
        const int cv = ((t4 * 2 + h) ^ swz8) * 8;                               \
        bf16x8 kf0 = *(const bf16x8*)&Kl[lq * 64 + cv];                         \
        bf16x8 kf1 = *(const bf16x8*)&Kl[(lq + 32) * 64 + cv];                  \
        sA0 = mfma32(kf0, qfA[t4], sA0);                                        \
        sB0 = mfma32(kf0, qfB[t4], sB0);                                        \
        sA1 = mfma32(kf1, qfA[t4], sA1);                                        \
        sB1 = mfma32(kf1, qfB[t4], sB1);                                        \
    }                                                                           \
    __builtin_amdgcn_s_setprio(0);                                              \
    float pA0[16], pA1[16], pB0[16], pB1[16];                                   \
    _Pragma("unroll")                                                           \
    for (int i = 0; i < 16; ++i) {                                              \
        pA0[i] = fexp2(sA0[i]); pA1[i] = fexp2(sA1[i]);                         \
        pB0[i] = fexp2(sB0[i]); pB1[i] = fexp2(sB1[i]);                         \
    }                                                                           \
    __builtin_amdgcn_s_setprio(1);                                              \
    PV2(pA0, pB0, 0, 0);                                                        \
    PV2(pA0, pB0, 8, 1);                                                        \
    PV2(pA1, pB1, 0, 2);                                                        \
    PV2(pA1, pB1, 8, 3);                                                        \
    __builtin_amdgcn_s_setprio(0);                                              \
    float a16[16], b16[16];                                                     \
    _Pragma("unroll")                                                           \
    for (int i = 0; i < 16; ++i) { a16[i] = pA0[i] + pA1[i]; b16[i] = pB0[i] + pB1[i]; } \
    _Pragma("unroll")                                                           \
    for (int i = 0; i < 8; ++i) { a16[i] += a16[i + 8]; b16[i] += b16[i + 8]; } \
    _Pragma("unroll")                                                           \
    for (int i = 0; i < 4; ++i) { a16[i] += a16[i + 4]; b16[i] += b16[i + 4]; } \
    float ltA = (a16[0] + a16[1]) + (a16[2] + a16[3]);                          \
    float ltB = (b16[0] + b16[1]) + (b16[2] + b16[3]);                          \
    ltA += __shfl_xor(ltA, 32);                                                 \
    ltB += __shfl_xor(ltB, 32);                                                 \
    lA += ltA;                                                                  \
    lB += ltB;                                                                  \
} while (0)

__global__ __launch_bounds__(256, 1) void r13_attn(
    const __bf16* __restrict__ qb, const __bf16* __restrict__ kb,
    const __bf16* __restrict__ vtb, __bf16* __restrict__ ctx)
{
    __shared__ __bf16 arena[16384];      // 32KB: KV dbuf; epilogue Os aliases it
    // XCD-aware swizzle: 4 heads x 8 qblks per XCD (per-XCD K/V = 2MB < L2)
    const int L = blockIdx.x + 8 * blockIdx.y;       // grid (8,32) -> 256 blocks
    const int xcd = L & 7, j = L >> 3;               // j in [0,32)
    const int bh = xcd * 4 + (j & 3);
    const int qblk = j >> 2;                         // [0,8)
    const int tid  = threadIdx.x;
    const int wave = tid >> 6, lane = tid & 63;
    const int lq = lane & 31, h = lane >> 5;
    const int swz8 = lq & 7;
    const int q0 = qblk * 256 + wave * 64;           // wave owns 64 q-rows

    const __bf16* Q  = qb  + ((size_t)bh * SL + q0) * HD;
    const __bf16* Kg = kb  + (size_t)bh * SL * HD;
    const __bf16* Vg = vtb + (size_t)bh * HD * SL;

    // staging geometry: thread owns 16B chunks (rA,cA) and (rA+32,cA)
    const int rA = tid >> 3, cA = tid & 7;
    const int sA = cA ^ (rA & 7);
    const int oA = rA * 64 + sA * 8;

    bf16x8 qfA[4], qfB[4];
#pragma unroll
    for (int t = 0; t < 4; ++t) {
        qfA[t] = *(const bf16x8*)&Q[(size_t)lq * HD + t * 16 + h * 8];
        qfB[t] = *(const bf16x8*)&Q[(size_t)(lq + 32) * HD + t * 16 + h * 8];
    }

    f32x16 accT0 = {}, accT1 = {}, accT2 = {}, accT3 = {};
    float lA = 0.f, lB = 0.f;

    const __bf16* KgA = Kg + (size_t)rA * HD + cA * 8;
    const __bf16* VgA = Vg + (size_t)rA * SL + cA * 8;
    // 2-deep prefetch: tiles 0 and 1 in two named register sets (rule #20)
    int4 kA0 = *(const int4*)(KgA);
    int4 kB0 = *(const int4*)(KgA + (size_t)32 * HD);
    int4 vA0 = *(const int4*)(VgA);
    int4 vB0 = *(const int4*)(VgA + (size_t)32 * SL);
    int4 kA1 = *(const int4*)(KgA + (size_t)64 * HD);
    int4 kB1 = *(const int4*)(KgA + (size_t)96 * HD);
    int4 vA1 = *(const int4*)(VgA + 64);
    int4 vB1 = *(const int4*)(VgA + (size_t)32 * SL + 64);

    constexpr int NT = SL / 64;          // 32 tiles
    for (int t = 0; t < NT; t += 2) {
        TILE_BODY(t,     kA0, kB0, vA0, vB0);
        TILE_BODY(t + 1, kA1, kB1, vA1, vB1);
    }

    // epilogue: KV arena dead -> per-wave transpose buffer, two passes (A then B)
    float invA = 1.f / lA, invB = 1.f / lB;
    __syncthreads();                      // full drain fine here (once)
    __bf16* Osw = &arena[wave * 2304];   // 32 rows x 72
    const int b = bh >> 4, head = bh & 15;
    const int qr = lane >> 1, seg = (lane & 1) * 32;
    // pass A: q-rows [q0, q0+32)
#pragma unroll
    for (int r = 0; r < 16; ++r) {
        int d0 = (r & 3) + 8 * (r >> 2) + 4 * h;
        Osw[lq * 72 + d0]      = (__bf16)(accT0[r] * invA);
        Osw[lq * 72 + 32 + d0] = (__bf16)(accT1[r] * invA);
    }
    asm volatile("s_waitcnt lgkmcnt(0)" ::: "memory");
    __builtin_amdgcn_sched_barrier(0);
    {
        __bf16* dst = &ctx[((size_t)b * SL + q0 + qr) * DM + head * HD + seg];
#pragma unroll
        for (int c = 0; c < 4; ++c)
            *(bf16x8*)&dst[c * 8] = *(const bf16x8*)&Osw[qr * 72 + seg + c * 8];
    }
    asm volatile("s_waitcnt lgkmcnt(0)" ::: "memory");
    __builtin_amdgcn_sched_barrier(0);
    // pass B: q-rows [q0+32, q0+64)
#pragma unroll
    for (int r = 0; r < 16; ++r) {
        int d0 = (r & 3) + 8 * (r >> 2) + 4 * h;
        Osw[lq * 72 + d0]      = (__bf16)(accT2[r] * invB);
        Osw[lq * 72 + 32 + d0] = (__bf16)(accT3[r] * invB);
    }
    asm volatile("s_waitcnt lgkmcnt(0)" ::: "memory");
    __builtin_amdgcn_sched_barrier(0);
    {
        __bf16* dst = &ctx[((size_t)b * SL + q0 + 32 + qr) * DM + head * HD + seg];
#pragma unroll
        for (int c = 0; c < 4; ++c)
            *(bf16x8*)&dst[c * 8] = *(const bf16x8*)&Osw[qr * 72 + seg + c * 8];
    }
}

extern "C" void kernel_launch(void* const* d_in, const int* in_sizes, int n_in,
                              void* d_out, int out_size, void* d_ws, size_t ws_size,
                              hipStream_t stream) {
    const float* x    = (const float*)d_in[0];
    const float* wqkv = (const float*)d_in[1];
    const float* wout = (const float*)d_in[2];
    float* out = (float*)d_out;                          // reference returns f32

    __bf16* ws    = (__bf16*)d_ws;
    __bf16* xb    = ws;                                  // 4M elems
    __bf16* wqkvT = xb    + (size_t)MROWS * DM;          // 3M
    __bf16* woutT = wqkvT + (size_t)3 * DM * DM;         // 1M
    __bf16* qbuf  = woutT + (size_t)DM * DM;             // 4M
    __bf16* kbuf  = qbuf  + (size_t)MROWS * DM;          // 4M
    __bf16* vtbuf = kbuf  + (size_t)MROWS * DM;          // 4M
    __bf16* ctxb  = vtbuf + (size_t)MROWS * DM;          // 4M (48MB total)

    r13_cast<<<dim3((MROWS * DM) / 1024), dim3(256), 0, stream>>>(x, xb, MROWS * DM);
    r13_transpose_cast<<<dim3(96, 32), dim3(256), 0, stream>>>(wqkv, wqkvT, DM, 3 * DM);
    r13_transpose_cast<<<dim3(32, 32), dim3(256), 0, stream>>>(wout, woutT, DM, DM);

    r13_gemm<1, 128><<<dim3(24, 32), dim3(256), 0, stream>>>(
        xb, wqkvT, (float*)nullptr, MROWS, 3 * DM, DM, qbuf, kbuf, vtbuf);

    r13_attn<<<dim3(8, 32), dim3(256), 0, stream>>>(qbuf, kbuf, vtbuf, ctxb);

    r13_gemm<0, 64><<<dim3(16, 32), dim3(256), 0, stream>>>(
        ctxb, woutT, out, MROWS, DM, DM,
        (__bf16*)nullptr, (__bf16*)nullptr, (__bf16*)nullptr);
}